// Round 7
// baseline (1059.283 us; speedup 1.0000x reference)
//
#include <hip/hip_runtime.h>
#include <hip/hip_fp16.h>
#include <math.h>

typedef _Float16 half8 __attribute__((ext_vector_type(8)));
typedef float f32x4 __attribute__((ext_vector_type(4)));

// ---------- helpers ----------
__device__ __forceinline__ float sspf(float v) {
    // shifted softplus, stable: max(v,0) + log1p(exp(-|v|)) - ln2
    float t = __expf(-fabsf(v));
    return fmaxf(v, 0.0f) + __logf(1.0f + t) - 0.693147180559945f;
}

// ---------- K0: weight prep — f16 transposed copies of filter weights ----------
__global__ __launch_bounds__(256) void prep_weights(const float* __restrict__ w1,
    const float* __restrict__ w2, _Float16* __restrict__ w1t, _Float16* __restrict__ w2t) {
    int i = blockIdx.x * 256 + threadIdx.x;
    if (i < 64 * 128) {                       // w1: [64 k][128 n] -> w1t[n][k]
        int n = i >> 6, k = i & 63;
        w1t[i] = (_Float16)w1[k * 128 + n];
    }
    int j = i - 64 * 128;
    if (j >= 0 && j < 128 * 128) {            // w2: [128 k][128 n] -> w2t[n][k]
        int n = j >> 7, k = j & 127;
        w2t[j] = (_Float16)w2[k * 128 + n];
    }
}

// ---------- CSR build: histogram -> exclusive scan -> scatter ----------
__global__ void hist_dst(const int* __restrict__ dst, int* __restrict__ deg, int E) {
    int e = blockIdx.x * 256 + threadIdx.x;
    if (e < E) atomicAdd(&deg[dst[e]], 1);
}

// single-block exclusive scan over n<=~64k ints (wave-shuffle based, 1024 thr)
__global__ __launch_bounds__(1024) void scan_exclusive(const int* __restrict__ deg,
    int* __restrict__ base, int n) {
    __shared__ int wsum[16];
    __shared__ int carry_s;
    const int t = threadIdx.x, lane = t & 63, wv = t >> 6;
    if (t == 0) carry_s = 0;
    __syncthreads();
    const int nch = (n + 1023) >> 10;
    for (int ch = 0; ch < nch; ++ch) {
        int i = (ch << 10) + t;
        int v = (i < n) ? deg[i] : 0;
        int inc = v;
        #pragma unroll
        for (int off = 1; off < 64; off <<= 1) {
            int u = __shfl_up(inc, off);
            if (lane >= off) inc += u;
        }
        if (lane == 63) wsum[wv] = inc;
        __syncthreads();
        if (wv == 0) {
            int s = (lane < 16) ? wsum[lane] : 0;
            #pragma unroll
            for (int off = 1; off < 16; off <<= 1) {
                int u = __shfl_up(s, off);
                if (lane >= off) s += u;
            }
            if (lane < 16) wsum[lane] = s;
        }
        __syncthreads();
        int carry = carry_s;
        int excl = carry + inc - v + (wv ? wsum[wv - 1] : 0);
        if (i < n) base[i] = excl;
        int total = wsum[15];
        __syncthreads();                 // everyone has read carry_s / wsum
        if (t == 0) carry_s = carry + total;
        __syncthreads();
    }
}

__global__ void scatter_perm(const int* __restrict__ dst, const int* __restrict__ base,
    int* __restrict__ cnt, int* __restrict__ perm, int E) {
    int e = blockIdx.x * 256 + threadIdx.x;
    if (e >= E) return;
    int d = dst[e];
    int p = base[d] + atomicAdd(&cnt[d], 1);
    perm[p] = e;
}

// ---------- K1: node projection, 64-node tiles, scalarized weights ----------
__global__ __launch_bounds__(256) void node_proj(const float* __restrict__ x,
    const float* __restrict__ fcw, const float* __restrict__ al, const float* __restrict__ ar,
    _Float16* __restrict__ featH, float* __restrict__ el, float* __restrict__ er, int N) {
    __shared__ float xs[64][65];
    __shared__ float pl[4][64], pr[4][64];
    const int tid = threadIdx.x, lane = tid & 63, w = tid >> 6;
    const int n0 = blockIdx.x * 64;
    const int nrows = min(64, N - n0);
    {   // stage x tile (coalesced float4)
        int r = tid >> 2, c0 = (tid & 3) * 16;
        if (r < nrows) {
            const float4* p = (const float4*)(x + (size_t)(n0 + r) * 64 + c0);
            #pragma unroll
            for (int q = 0; q < 4; ++q) {
                float4 v = p[q];
                xs[r][c0 + q * 4 + 0] = v.x; xs[r][c0 + q * 4 + 1] = v.y;
                xs[r][c0 + q * 4 + 2] = v.z; xs[r][c0 + q * 4 + 3] = v.w;
            }
        }
    }
    __syncthreads();
    const int c0w = w * 32;
    float acc[32];
    #pragma unroll
    for (int c = 0; c < 32; ++c) acc[c] = 0.f;
    #pragma unroll 4
    for (int k = 0; k < 64; ++k) {
        float xv = xs[lane][k];
        const float* wr = &fcw[k * 128 + c0w];
        #pragma unroll
        for (int c = 0; c < 32; ++c) acc[c] = fmaf(xv, wr[c], acc[c]);
    }
    if (lane < nrows) {
        _Float16* fp = featH + (size_t)(n0 + lane) * 128 + c0w;
        #pragma unroll
        for (int c = 0; c < 32; ++c) fp[c] = (_Float16)acc[c];
    }
    float vl = 0.f, vr = 0.f;
    #pragma unroll
    for (int c = 0; c < 32; ++c) {
        vl = fmaf(acc[c], al[c0w + c], vl);
        vr = fmaf(acc[c], ar[c0w + c], vr);
    }
    pl[w][lane] = vl; pr[w][lane] = vr;
    __syncthreads();
    if (w == 0 && lane < nrows)
        ((float2*)el)[n0 + lane] = make_float2(pl[0][lane] + pl[1][lane],
                                               pl[2][lane] + pl[3][lane]);
    if (w == 1 && lane < nrows)
        ((float2*)er)[n0 + lane] = make_float2(pr[0][lane] + pr[1][lane],
                                               pr[2][lane] + pr[3][lane]);
}

// ---------- K4: fused edge kernel (dst-sorted order) ----------
// scores+exp+den fused in (deferred-den: agg_raw = sum ex*cut*filt*feat; divide in out_head).
// Epilogue: thread=(col,32-edge strip), run-merged atomics on sorted dst (wave-uniform branch).
__global__ __launch_bounds__(256) void edge_filter_mfma(
    const float* __restrict__ gs, const float* __restrict__ rij,
    const int* __restrict__ src, const int* __restrict__ dst,
    const int* __restrict__ perm,
    const _Float16* __restrict__ w1t, const float* __restrict__ b1,
    const _Float16* __restrict__ w2t, const float* __restrict__ b2,
    const _Float16* __restrict__ featH, const float* __restrict__ el,
    const float* __restrict__ er, float* __restrict__ den, float* __restrict__ agg) {
    __shared__ _Float16 sGS[64][72];    // +8 pad
    __shared__ _Float16 sH[64][136];    // GEMM1 out / GEMM2 A; then reused for F (f16)
    __shared__ float coefs[2][64];
    __shared__ int seid[64];
    __shared__ int ssrc[64], sdst[64];
    const int tid  = threadIdx.x;
    const int lane = tid & 63;
    const int w    = tid >> 6;
    const int e0   = blockIdx.x * 64;
    const int ln   = lane & 15;
    const int kq   = (lane >> 4) * 8;

    if (tid < 64) seid[tid] = perm[e0 + tid];
    __syncthreads();

    if (w == 0) {   // per-edge: score -> exp -> den atomic; coef = ex*cut (den deferred)
        int eid = seid[lane];
        int sv = src[eid], dv = dst[eid];
        ssrc[lane] = sv; sdst[lane] = dv;
        float rv = rij[eid];
        float cut = (rv < 5.0f) ? 0.5f * (cosf(0.6283185307179586f * rv) + 1.0f) : 0.0f;
        float2 a = ((const float2*)el)[sv];
        float2 b = ((const float2*)er)[dv];
        float s0 = a.x + b.x; s0 = (s0 > 0.f) ? s0 : 0.2f * s0;
        float s1 = a.y + b.y; s1 = (s1 > 0.f) ? s1 : 0.2f * s1;
        float x0 = __expf(s0), x1 = __expf(s1);
        unsafeAtomicAdd(&den[2 * dv],     x0);
        unsafeAtomicAdd(&den[2 * dv + 1], x1);
        coefs[0][lane] = x0 * cut;
        coefs[1][lane] = x1 * cut;
    }
    {   // stage gs rows (permuted) -> f16 LDS; 4 threads per row
        int r = tid >> 2, c0 = (tid & 3) * 16;
        const float4* g4 = (const float4*)(gs + (size_t)seid[r] * 64 + c0);
        #pragma unroll
        for (int q = 0; q < 4; ++q) {
            float4 v = g4[q];
            sGS[r][c0 + q * 4 + 0] = (_Float16)v.x;
            sGS[r][c0 + q * 4 + 1] = (_Float16)v.y;
            sGS[r][c0 + q * 4 + 2] = (_Float16)v.z;
            sGS[r][c0 + q * 4 + 3] = (_Float16)v.w;
        }
    }
    __syncthreads();

    const int mrow = (w << 4) + ln;

    // ---- GEMM1: [64,64] @ [64,128] ----
    f32x4 acc[8];
    #pragma unroll
    for (int nt = 0; nt < 8; ++nt) acc[nt] = (f32x4){0.f, 0.f, 0.f, 0.f};
    #pragma unroll
    for (int kk = 0; kk < 2; ++kk) {
        half8 a = *(const half8*)&sGS[mrow][kk * 32 + kq];
        #pragma unroll
        for (int nt = 0; nt < 8; ++nt) {
            half8 b = *(const half8*)&w1t[(nt * 16 + ln) * 64 + kk * 32 + kq];
            acc[nt] = __builtin_amdgcn_mfma_f32_16x16x32_f16(a, b, acc[nt], 0, 0, 0);
        }
    }
    #pragma unroll
    for (int nt = 0; nt < 8; ++nt) {
        int col = nt * 16 + ln;
        float bias = b1[col];
        #pragma unroll
        for (int r = 0; r < 4; ++r) {
            int erow = (w << 4) + ((lane >> 4) << 2) + r;
            sH[erow][col] = (_Float16)sspf(acc[nt][r] + bias);
        }
    }

    // ---- GEMM2: [64,128] @ [128,128] (each wave reads only its own 16 sH rows) ----
    f32x4 facc[8];
    #pragma unroll
    for (int nt = 0; nt < 8; ++nt) facc[nt] = (f32x4){0.f, 0.f, 0.f, 0.f};
    #pragma unroll
    for (int kk = 0; kk < 4; ++kk) {
        half8 a = *(const half8*)&sH[mrow][kk * 32 + kq];
        #pragma unroll
        for (int nt = 0; nt < 8; ++nt) {
            half8 b = *(const half8*)&w2t[(nt * 16 + ln) * 128 + kk * 32 + kq];
            facc[nt] = __builtin_amdgcn_mfma_f32_16x16x32_f16(a, b, facc[nt], 0, 0, 0);
        }
    }
    // write F = facc + b2 into own sH rows (facc depends on all A reads -> no race)
    #pragma unroll
    for (int nt = 0; nt < 8; ++nt) {
        int col = nt * 16 + ln;
        float bias = b2[col];
        #pragma unroll
        for (int r = 0; r < 4; ++r) {
            int erow = (w << 4) + ((lane >> 4) << 2) + r;
            sH[erow][col] = (_Float16)(facc[nt][r] + bias);
        }
    }
    __syncthreads();

    // ---- epilogue: thread = (col, 32-edge strip); run-merged atomics on sorted dst ----
    {
        const int col  = tid & 127;
        const int r0   = (tid >> 7) * 32;
        const int hsel = col >> 6;
        float acc2 = 0.f;
        int dprev = sdst[r0];
        #pragma unroll 8
        for (int r = r0; r < r0 + 32; ++r) {
            int dcur = sdst[r];                       // wave-uniform
            if (dcur != dprev) {                      // wave-uniform branch
                unsafeAtomicAdd(&agg[(size_t)dprev * 128 + col], acc2);
                acc2 = 0.f; dprev = dcur;
            }
            float fv = (float)sH[r][col];
            float m  = fv * coefs[hsel][r] * (float)featH[(size_t)ssrc[r] * 128 + col];
            acc2 += m;
        }
        unsafeAtomicAdd(&agg[(size_t)dprev * 128 + col], acc2);
    }
}

// ---------- K5: output head (divides agg_raw by den), 64-node tiles ----------
__global__ __launch_bounds__(256) void out_head(const float* __restrict__ agg,
    const float* __restrict__ den,
    const float* __restrict__ w1, const float* __restrict__ b1,
    const float* __restrict__ w2, const float* __restrict__ b2,
    float* __restrict__ out, int N) {
    __shared__ float a2[64][129];
    __shared__ float ts[64][65];
    const int tid = threadIdx.x, lane = tid & 63, w = tid >> 6;
    const int n0 = blockIdx.x * 64;
    const int nrows = min(64, N - n0);
    {   // stage ssp(agg/den) tile
        int r = tid >> 2, c0 = (tid & 3) * 32;
        if (r < nrows) {
            int h = c0 >> 6;   // head is uniform per thread (c0 in {0,32,64,96})
            float inv = 1.0f / fmaxf(den[(size_t)(n0 + r) * 2 + h], 1e-16f);
            const float4* p = (const float4*)(agg + (size_t)(n0 + r) * 128 + c0);
            #pragma unroll
            for (int q = 0; q < 8; ++q) {
                float4 v = p[q];
                a2[r][c0 + q * 4 + 0] = sspf(v.x * inv);
                a2[r][c0 + q * 4 + 1] = sspf(v.y * inv);
                a2[r][c0 + q * 4 + 2] = sspf(v.z * inv);
                a2[r][c0 + q * 4 + 3] = sspf(v.w * inv);
            }
        }
    }
    __syncthreads();
    const int c0w = w * 16;
    float acc[16];
    #pragma unroll
    for (int c = 0; c < 16; ++c) acc[c] = b1[c0w + c];
    #pragma unroll 4
    for (int k = 0; k < 128; ++k) {
        float av = a2[lane][k];
        const float* wr = &w1[k * 64 + c0w];
        #pragma unroll
        for (int c = 0; c < 16; ++c) acc[c] = fmaf(av, wr[c], acc[c]);
    }
    #pragma unroll
    for (int c = 0; c < 16; ++c) ts[lane][c0w + c] = sspf(acc[c]);
    __syncthreads();
    float o[16];
    #pragma unroll
    for (int c = 0; c < 16; ++c) o[c] = b2[c0w + c];
    #pragma unroll 4
    for (int k = 0; k < 64; ++k) {
        float av = ts[lane][k];
        const float* wr = &w2[k * 64 + c0w];
        #pragma unroll
        for (int c = 0; c < 16; ++c) o[c] = fmaf(av, wr[c], o[c]);
    }
    if (lane < nrows) {
        float* op = out + (size_t)(n0 + lane) * 64 + c0w;
        #pragma unroll
        for (int q = 0; q < 4; ++q)
            ((float4*)op)[q] = make_float4(o[q*4], o[q*4+1], o[q*4+2], o[q*4+3]);
    }
}

// ---------- launch ----------
extern "C" void kernel_launch(void* const* d_in, const int* in_sizes, int n_in,
                              void* d_out, int out_size, void* d_ws, size_t ws_size,
                              hipStream_t stream) {
    const float* x   = (const float*)d_in[0];
    const float* gs  = (const float*)d_in[1];
    const float* rij = (const float*)d_in[2];
    const int*   src = (const int*)d_in[3];
    const int*   dst = (const int*)d_in[4];
    const float* fcw = (const float*)d_in[5];
    const float* al  = (const float*)d_in[6];
    const float* ar  = (const float*)d_in[7];
    const float* fw1 = (const float*)d_in[8];
    const float* fb1 = (const float*)d_in[9];
    const float* fw2 = (const float*)d_in[10];
    const float* fb2 = (const float*)d_in[11];
    const float* mw1 = (const float*)d_in[12];
    const float* mb1 = (const float*)d_in[13];
    const float* mw2 = (const float*)d_in[14];
    const float* mb2 = (const float*)d_in[15];
    float* outp = (float*)d_out;

    const int N = in_sizes[0] / 64;   // 50000
    const int E = in_sizes[2];        // 800000

    // ws layout: featH[N*128 f16] | el[N*2] er[N*2] | den[N*2] agg[N*128] deg[N] cnt[N]
    //            (den..cnt zeroed in ONE memset) | base[N] perm[E] | w1t w2t (f16)
    _Float16* featH = (_Float16*)d_ws;
    float*    el   = (float*)(featH + (size_t)N * 128);
    float*    er   = el   + (size_t)N * 2;
    float*    den  = er   + (size_t)N * 2;
    float*    agg  = den  + (size_t)N * 2;
    int*      deg  = (int*)(agg + (size_t)N * 128);
    int*      cnt  = deg  + N;
    int*      base = cnt  + N;
    int*      perm = base + N;
    _Float16* w1t  = (_Float16*)(perm + E);
    _Float16* w2t  = w1t + 64 * 128;

    // zero den + agg + deg + cnt in one contiguous memset (N*132 words)
    hipMemsetAsync(den, 0, (size_t)N * 132 * sizeof(float), stream);

    prep_weights    <<<96, 256, 0, stream>>>(fw1, fw2, w1t, w2t);
    hist_dst        <<<(E + 255) / 256, 256, 0, stream>>>(dst, deg, E);
    scan_exclusive  <<<1, 1024, 0, stream>>>(deg, base, N);
    scatter_perm    <<<(E + 255) / 256, 256, 0, stream>>>(dst, base, cnt, perm, E);
    node_proj       <<<(N + 63) / 64, 256, 0, stream>>>(x, fcw, al, ar, featH, el, er, N);
    edge_filter_mfma<<<E / 64, 256, 0, stream>>>(gs, rij, src, dst, perm, w1t, fb1,
                                                 w2t, fb2, featH, el, er, den, agg);
    out_head        <<<(N + 63) / 64, 256, 0, stream>>>(agg, den, mw1, mb1, mw2, mb2, outp, N);
}